// Round 1
// baseline (542.680 us; speedup 1.0000x reference)
//
#include <hip/hip_runtime.h>
#include <hip/hip_bf16.h>
#include <math.h>

typedef __attribute__((ext_vector_type(8))) short short8;
typedef __attribute__((ext_vector_type(4))) float f32x4;

// Problem constants: B=4, S=1024, H=16, d_k=64, d_model=1024.

static __device__ __forceinline__ unsigned short f2bf(float x) {
  union { float f; unsigned u; } v; v.f = x;
  unsigned r = v.u + 0x7fffu + ((v.u >> 16) & 1u);   // RNE
  return (unsigned short)(r >> 16);
}

// ---------------------------------------------------------------------------
// Kernel 1: per-head projections.  Q,K stored [b,h,s,64] bf16; V stored
// transposed [b,h,d,s] bf16 so the attention kernel's PV B-operand is a
// contiguous row read (no LDS transpose there).
// grid (16 s-tiles, 16 heads, 12 = which*4+b), block 256.
// ---------------------------------------------------------------------------
__global__ __launch_bounds__(256) void proj_kernel(
    const float* __restrict__ q_in, const float* __restrict__ k_in,
    const float* __restrict__ v_in, const float* __restrict__ Wq,
    const float* __restrict__ Wk, const float* __restrict__ Wv,
    unsigned short* __restrict__ qws, unsigned short* __restrict__ kws,
    unsigned short* __restrict__ vws) {
  __shared__ unsigned short As[64 * 72];   // X tile, rows s, cols k (bf16)
  __shared__ unsigned short Bs[64 * 72];   // W^T tile, rows n, cols k (bf16)
  const int tid = threadIdx.x;
  const int s0 = blockIdx.x * 64;
  const int h = blockIdx.y;
  const int b = blockIdx.z & 3;
  const int which = blockIdx.z >> 2;       // 0=Q 1=K 2=V
  const float* X = which == 0 ? q_in : (which == 1 ? k_in : v_in);
  const float* W = which == 0 ? Wq : (which == 1 ? Wk : Wv);

  const int w = tid >> 6, lane = tid & 63, q16 = lane & 15, quad = lane >> 4;

  f32x4 acc[4];
  #pragma unroll
  for (int j = 0; j < 4; ++j) acc[j] = (f32x4)0.0f;

  for (int kt = 0; kt < 16; ++kt) {
    // stage X tile (64 rows x 64 cols), f32 -> bf16
    #pragma unroll
    for (int p = 0; p < 4; ++p) {
      int idx = tid + p * 256;
      int r = idx >> 4, c4 = idx & 15;
      const float4 v = *(const float4*)(X + (size_t)(b * 1024 + s0 + r) * 1024 + kt * 64 + c4 * 4);
      ushort4 u;
      u.x = f2bf(v.x); u.y = f2bf(v.y); u.z = f2bf(v.z); u.w = f2bf(v.w);
      *(ushort4*)&As[r * 72 + c4 * 4] = u;
    }
    // stage W^T tile: Bs[n][d_local] = W[h, kt*64+d_local, n]
    #pragma unroll
    for (int p = 0; p < 16; ++p) {
      int dl = p * 4 + (tid >> 6);
      int n = tid & 63;
      float wv = W[(size_t)h * 65536 + (size_t)(kt * 64 + dl) * 64 + n];
      Bs[n * 72 + dl] = f2bf(wv);
    }
    __syncthreads();
    #pragma unroll
    for (int kk = 0; kk < 2; ++kk) {
      short8 a = *(const short8*)&As[(w * 16 + q16) * 72 + kk * 32 + quad * 8];
      #pragma unroll
      for (int j = 0; j < 4; ++j) {
        short8 bb = *(const short8*)&Bs[(j * 16 + q16) * 72 + kk * 32 + quad * 8];
        acc[j] = __builtin_amdgcn_mfma_f32_16x16x32_bf16(a, bb, acc[j], 0, 0, 0);
      }
    }
    __syncthreads();
  }

  const size_t bh = (size_t)(b * 16 + h);
  #pragma unroll
  for (int j = 0; j < 4; ++j) {
    #pragma unroll
    for (int r = 0; r < 4; ++r) {
      int sl = w * 16 + quad * 4 + r;       // C/D: row = quad*4+reg (+ wave row base)
      int ko = j * 16 + q16;                // C/D: col = lane&15 (+ 16*j)
      unsigned short val = f2bf(acc[j][r]);
      if (which == 2)
        vws[(bh * 64 + ko) * 1024 + (s0 + sl)] = val;        // V^T: [b,h,d,s]
      else if (which == 1)
        kws[(bh * 1024 + (s0 + sl)) * 64 + ko] = val;        // [b,h,s,d]
      else
        qws[(bh * 1024 + (s0 + sl)) * 64 + ko] = val;
    }
  }
}

// ---------------------------------------------------------------------------
// Kernel 2: flash-style attention per (q-tile 64, h, b).  Writes masked
// scores (fp32) to d_out once; accumulates O with online softmax; writes
// concat [b, s, h*64+d] bf16 to d_ws.
// grid (16, 16, 4), block 256.
// ---------------------------------------------------------------------------
__global__ __launch_bounds__(256) void attn_kernel(
    const unsigned short* __restrict__ qws, const unsigned short* __restrict__ kws,
    const unsigned short* __restrict__ vws, const int* __restrict__ mask,
    float* __restrict__ scores, unsigned short* __restrict__ cws) {
  __shared__ unsigned short Qs[64 * 72];
  __shared__ unsigned short Ks[64 * 72];
  __shared__ unsigned short Vts[64 * 72];
  __shared__ unsigned short Ps[64 * 72];
  const int tid = threadIdx.x;
  const int q0 = blockIdx.x * 64;
  const int h = blockIdx.y;
  const int b = blockIdx.z;
  const int w = tid >> 6, lane = tid & 63, q16 = lane & 15, quad = lane >> 4;
  const size_t bh = (size_t)(b * 16 + h);

  // stage Q tile once
  {
    const unsigned short* src = qws + (bh * 1024 + q0) * 64;
    #pragma unroll
    for (int p = 0; p < 2; ++p) {
      int idx = tid + p * 256, r = idx >> 3, c = idx & 7;
      *(uint4*)&Qs[r * 72 + c * 8] = *(const uint4*)(src + r * 64 + c * 8);
    }
  }

  f32x4 o[4];
  #pragma unroll
  for (int j = 0; j < 4; ++j) o[j] = (f32x4)0.0f;
  float m_run[4] = {-3.0e38f, -3.0e38f, -3.0e38f, -3.0e38f};
  float l_run[4] = {0.f, 0.f, 0.f, 0.f};

  for (int kt = 0; kt < 16; ++kt) {
    // stage K tile [key][d] and V^T tile [d][key]
    {
      const unsigned short* ksrc = kws + (bh * 1024 + (size_t)kt * 64) * 64;
      const unsigned short* vsrc = vws + bh * 64 * 1024 + kt * 64;
      #pragma unroll
      for (int p = 0; p < 2; ++p) {
        int idx = tid + p * 256, r = idx >> 3, c = idx & 7;
        *(uint4*)&Ks[r * 72 + c * 8] = *(const uint4*)(ksrc + r * 64 + c * 8);
        *(uint4*)&Vts[r * 72 + c * 8] = *(const uint4*)(vsrc + (size_t)r * 1024 + c * 8);
      }
    }
    __syncthreads();

    // S = Q K^T  (B-operand fragment = K rows: B[k=d][n=key])
    f32x4 sacc[4];
    #pragma unroll
    for (int j = 0; j < 4; ++j) sacc[j] = (f32x4)0.0f;
    #pragma unroll
    for (int kk = 0; kk < 2; ++kk) {
      short8 a = *(const short8*)&Qs[(w * 16 + q16) * 72 + kk * 32 + quad * 8];
      #pragma unroll
      for (int j = 0; j < 4; ++j) {
        short8 bb = *(const short8*)&Ks[(j * 16 + q16) * 72 + kk * 32 + quad * 8];
        sacc[j] = __builtin_amdgcn_mfma_f32_16x16x32_bf16(a, bb, sacc[j], 0, 0, 0);
      }
    }

    // scale, mask, write masked scores (fp32, once), track row max
    float rm[4] = {-3.0e38f, -3.0e38f, -3.0e38f, -3.0e38f};
    #pragma unroll
    for (int j = 0; j < 4; ++j) {
      #pragma unroll
      for (int r = 0; r < 4; ++r) {
        int ql = w * 16 + quad * 4 + r;
        int q = q0 + ql;
        int key = kt * 64 + j * 16 + q16;
        int mk = mask[((size_t)b * 1024 + q) * 1024 + key];
        float sv = sacc[j][r] * 0.125f;
        scores[(((size_t)h * 4 + b) * 1024 + q) * 1024 + key] = mk ? sv : -INFINITY;
        sv = mk ? sv : -3.0e38f;   // finite sentinel for softmax math
        sacc[j][r] = sv;
        rm[r] = fmaxf(rm[r], sv);
      }
    }
    // row-max across the 16 lanes of each quad (rows = quad*4+reg)
    #pragma unroll
    for (int mM = 1; mM <= 8; mM <<= 1) {
      #pragma unroll
      for (int r = 0; r < 4; ++r) rm[r] = fmaxf(rm[r], __shfl_xor(rm[r], mM));
    }
    float rs[4];
    #pragma unroll
    for (int r = 0; r < 4; ++r) {
      float mnew = fmaxf(m_run[r], rm[r]);
      float alpha = __expf(m_run[r] - mnew);
      m_run[r] = mnew;
      l_run[r] *= alpha;
      #pragma unroll
      for (int j = 0; j < 4; ++j) o[j][r] *= alpha;
      rs[r] = 0.f;
    }
    // P = exp(S - m), write bf16 to LDS in A-operand row layout
    #pragma unroll
    for (int j = 0; j < 4; ++j) {
      #pragma unroll
      for (int r = 0; r < 4; ++r) {
        float p = __expf(sacc[j][r] - m_run[r]);
        rs[r] += p;
        int ql = w * 16 + quad * 4 + r;
        Ps[ql * 72 + j * 16 + q16] = f2bf(p);
      }
    }
    #pragma unroll
    for (int mM = 1; mM <= 8; mM <<= 1) {
      #pragma unroll
      for (int r = 0; r < 4; ++r) rs[r] += __shfl_xor(rs[r], mM);
    }
    #pragma unroll
    for (int r = 0; r < 4; ++r) l_run[r] += rs[r];
    __syncthreads();   // Ps visible before PV (wave-local rows, but be safe)

    // O += P V   (B-operand fragment = V^T rows: B[k=key][n=d])
    #pragma unroll
    for (int kk = 0; kk < 2; ++kk) {
      short8 a = *(const short8*)&Ps[(w * 16 + q16) * 72 + kk * 32 + quad * 8];
      #pragma unroll
      for (int j = 0; j < 4; ++j) {
        short8 bb = *(const short8*)&Vts[(j * 16 + q16) * 72 + kk * 32 + quad * 8];
        o[j] = __builtin_amdgcn_mfma_f32_16x16x32_bf16(a, bb, o[j], 0, 0, 0);
      }
    }
    __syncthreads();   // done with Ks/Vts/Ps before next stage
  }

  float inv[4];
  #pragma unroll
  for (int r = 0; r < 4; ++r) inv[r] = 1.0f / l_run[r];
  #pragma unroll
  for (int j = 0; j < 4; ++j) {
    #pragma unroll
    for (int r = 0; r < 4; ++r) {
      int ql = w * 16 + quad * 4 + r;
      int d = j * 16 + q16;
      cws[((size_t)(b * 1024 + q0 + ql)) * 1024 + h * 64 + d] = f2bf(o[j][r] * inv[r]);
    }
  }
}

// ---------------------------------------------------------------------------
// Kernel 3: out = concat(bf16) @ Wo(f32->bf16), fp32 out.
// grid (64 m-tiles, 16 n-tiles), block 256.
// ---------------------------------------------------------------------------
__global__ __launch_bounds__(256) void outproj_kernel(
    const unsigned short* __restrict__ cws, const float* __restrict__ Wo,
    float* __restrict__ out) {
  __shared__ unsigned short As[64 * 72];
  __shared__ unsigned short Bs[64 * 72];
  const int tid = threadIdx.x;
  const int m0 = blockIdx.x * 64;
  const int n0 = blockIdx.y * 64;
  const int w = tid >> 6, lane = tid & 63, q16 = lane & 15, quad = lane >> 4;
  f32x4 acc[4];
  #pragma unroll
  for (int j = 0; j < 4; ++j) acc[j] = (f32x4)0.0f;

  for (int kt = 0; kt < 16; ++kt) {
    #pragma unroll
    for (int p = 0; p < 2; ++p) {
      int idx = tid + p * 256, r = idx >> 3, c = idx & 7;
      *(uint4*)&As[r * 72 + c * 8] = *(const uint4*)(cws + (size_t)(m0 + r) * 1024 + kt * 64 + c * 8);
    }
    #pragma unroll
    for (int p = 0; p < 16; ++p) {
      int kr = p * 4 + (tid >> 6);
      int n = tid & 63;
      Bs[n * 72 + kr] = f2bf(Wo[(size_t)(kt * 64 + kr) * 1024 + n0 + n]);
    }
    __syncthreads();
    #pragma unroll
    for (int kk = 0; kk < 2; ++kk) {
      short8 a = *(const short8*)&As[(w * 16 + q16) * 72 + kk * 32 + quad * 8];
      #pragma unroll
      for (int j = 0; j < 4; ++j) {
        short8 bb = *(const short8*)&Bs[(j * 16 + q16) * 72 + kk * 32 + quad * 8];
        acc[j] = __builtin_amdgcn_mfma_f32_16x16x32_bf16(a, bb, acc[j], 0, 0, 0);
      }
    }
    __syncthreads();
  }
  #pragma unroll
  for (int j = 0; j < 4; ++j) {
    #pragma unroll
    for (int r = 0; r < 4; ++r) {
      out[(size_t)(m0 + w * 16 + quad * 4 + r) * 1024 + n0 + j * 16 + q16] = acc[j][r];
    }
  }
}

extern "C" void kernel_launch(void* const* d_in, const int* in_sizes, int n_in,
                              void* d_out, int out_size, void* d_ws, size_t ws_size,
                              hipStream_t stream) {
  (void)in_sizes; (void)n_in; (void)out_size; (void)ws_size;
  const float* q_in = (const float*)d_in[0];
  const float* k_in = (const float*)d_in[1];
  const float* v_in = (const float*)d_in[2];
  const int* mask   = (const int*)d_in[3];
  const float* Wq   = (const float*)d_in[4];
  const float* Wk   = (const float*)d_in[5];
  const float* Wv   = (const float*)d_in[6];
  const float* Wo   = (const float*)d_in[7];

  float* out = (float*)d_out;                         // [4,1024,1024]
  float* scores = out + (size_t)4 * 1024 * 1024;      // [16,4,1024,1024]

  // workspace: Q,K,V (bf16, 8.39 MB each) + concat (bf16, 8.39 MB) = 33.6 MB
  unsigned short* qws = (unsigned short*)d_ws;
  unsigned short* kws = qws + (size_t)4 * 16 * 1024 * 64;
  unsigned short* vws = kws + (size_t)4 * 16 * 1024 * 64;
  unsigned short* cws = vws + (size_t)4 * 16 * 1024 * 64;

  proj_kernel<<<dim3(16, 16, 12), 256, 0, stream>>>(q_in, k_in, v_in, Wq, Wk, Wv, qws, kws, vws);
  attn_kernel<<<dim3(16, 16, 4), 256, 0, stream>>>(qws, kws, vws, mask, scores, cws);
  outproj_kernel<<<dim3(64, 16), 256, 0, stream>>>(cws, Wo, out);
}